// Round 4
// baseline (691.286 us; speedup 1.0000x reference)
//
#include <hip/hip_runtime.h>
#include <hip/hip_bf16.h>
#include <math.h>

#define NS 4096      // samples
#define NC 512       // clusters
#define ND 64        // feature dim
#define NK 10        // classes
#define NPAIR 2080   // upper-triangle pairs (e<=d) of 64x64
#define KP 2176      // 2080 + 64 (linear) + 1 (const) + 31 zero-pad; 68*32
#define BOFF 2080
#define KOFF 2144
#define KT_STEPS (KP / 32)   // 68

typedef __attribute__((ext_vector_type(8))) short short8;
typedef __attribute__((ext_vector_type(8))) unsigned short ushort8;
typedef __attribute__((ext_vector_type(4))) float floatx4;

__device__ inline unsigned short f2b(float x) {
    __hip_bfloat16 h = __float2bfloat16(x);           // RNE
    return __builtin_bit_cast(unsigned short, h);
}
__device__ inline float b2f(unsigned short u) {
    __hip_bfloat16 h = __builtin_bit_cast(__hip_bfloat16, u);
    return __bfloat162float(h);
}

// ---------------- pair-index tables ----------------
__global__ void table_kernel(int* __restrict__ eop, int* __restrict__ dop) {
    const int e = threadIdx.x;                        // 64 threads
    int off = e * 64 - (e * (e - 1)) / 2;             // row e starts here
    for (int d = e; d < 64; ++d) { eop[off + d - e] = e; dop[off + d - e] = d; }
}

// ---------------- Sigma^-1: barrier-free wave-per-matrix in-place Gauss-Jordan ----
// One wave per cluster. Lane j owns column j; A[i] (reg) = A[i][j].
// launch_bounds(64,1): 1 wave/EU -> ~512 VGPR budget. R3 showed that without
// this the allocator caps at 72 VGPRs and spills A[] to scratch (535 us).
__global__ __launch_bounds__(64, 1) void prep_kernel(
    const float* __restrict__ S, const float* __restrict__ n,
    const float* __restrict__ mu, const int* __restrict__ clab,
    float* __restrict__ Binv, float* __restrict__ bvec,
    float* __restrict__ kcon, float* __restrict__ labf)
{
    const int c = blockIdx.x;
    const int j = threadIdx.x;                        // column owned by this lane

    const float inv_nc = 1.0f / n[c];
    float A[ND];
    #pragma unroll
    for (int i = 0; i < ND; ++i) {
        float v = S[(size_t)c * ND * ND + i * ND + j] * inv_nc;  // Sigma = S/n
        if (i == j) v += 1e-6f;                                   // + eps*I
        A[i] = v;
    }

    #pragma unroll
    for (int k = 0; k < ND; ++k) {
        const float p  = __shfl(A[k], k);             // pivot A[k][k] (readlane, k literal)
        const float ip = 1.0f / p;
        A[k] = (j == k ? 1.0f : A[k]) * ip;           // row k: implicit identity col
        #pragma unroll
        for (int i = 0; i < ND; ++i) {
            if (i == k) continue;
            const float f = __shfl(A[i], k);          // A[i][k] pre-update (wave-sync)
            A[i] = (j == k ? 0.0f : A[i]) - f * A[k];
        }
    }

    #pragma unroll
    for (int i = 0; i < ND; ++i)                      // coalesced: lane j = col j
        Binv[(size_t)c * ND * ND + i * ND + j] = A[i];

    // y = Sinv * mu via transpose trick (Sinv symmetric): y[j] = sum_i A[i][j]*mu[i]
    // mu[c*ND+i] is wave-uniform -> scalar loads + FMA-with-SGPR.
    float y = 0.f;
    #pragma unroll
    for (int i = 0; i < ND; ++i)
        y += A[i] * mu[c * ND + i];
    bvec[c * ND + j] = -2.0f * y;

    float kk = mu[c * ND + j] * y;                    // kcon = mu . y
    #pragma unroll
    for (int off = 32; off > 0; off >>= 1) kk += __shfl_down(kk, off);
    if (j == 0) {
        kcon[c] = kk;
        int lab = 0;
        for (int q = 0; q < NK; ++q) if (clab[c * NK + q] != 0) lab = q;
        labf[c] = (float)lab;
    }
}

// ---------------- pack beta_c = [sym-folded Binv, b, k, 0pad] as bf16 hi/lo ----------------
__global__ __launch_bounds__(256) void pack_kernel(
    const float* __restrict__ Binv, const float* __restrict__ bvec,
    const float* __restrict__ kcon, const int* __restrict__ eop,
    const int* __restrict__ dop, unsigned short* __restrict__ Bph,
    unsigned short* __restrict__ Bpl)
{
    const int c = blockIdx.x;
    const float* __restrict__ B = Binv + (size_t)c * ND * ND;
    for (int p = threadIdx.x; p < KP; p += 256) {
        float val;
        if (p < NPAIR) {
            const int e = eop[p], d = dop[p];
            val = (e == d) ? B[e * 64 + e] : (B[e * 64 + d] + B[d * 64 + e]);
        } else if (p < KOFF) val = bvec[c * ND + (p - BOFF)];
        else if (p == KOFF)  val = kcon[c];
        else                 val = 0.f;
        const unsigned short h = f2b(val);
        const unsigned short l = f2b(val - b2f(h));
        Bph[(size_t)c * KP + p] = h;
        Bpl[(size_t)c * KP + p] = l;
    }
}

// ---------------- Q rows: [z_e*z_d (e<=d), z, 1, 0pad] as bf16 hi/lo ----------------
__global__ __launch_bounds__(256) void qbuild_kernel(
    const float* __restrict__ data, const int* __restrict__ eop,
    const int* __restrict__ dop, unsigned short* __restrict__ Qh,
    unsigned short* __restrict__ Ql)
{
    const int s = blockIdx.x;
    __shared__ float z[ND];
    if (threadIdx.x < ND) z[threadIdx.x] = data[(size_t)s * ND + threadIdx.x];
    __syncthreads();
    for (int p = threadIdx.x; p < KP; p += 256) {
        float val;
        if (p < NPAIR)      val = z[eop[p]] * z[dop[p]];
        else if (p < KOFF)  val = z[p - BOFF];
        else if (p == KOFF) val = 1.0f;
        else                val = 0.f;
        const unsigned short h = f2b(val);
        const unsigned short l = f2b(val - b2f(h));
        Qh[(size_t)s * KP + p] = h;
        Ql[(size_t)s * KP + p] = l;
    }
}

// ---------------- d2[s][c] = Q · Beta^T via bf16x3 MFMA ----------------
// Block tile: 32 samples x 256 clusters, K-chunk 32, 4 waves (each 32x64).
__global__ __launch_bounds__(256) void gemm_kernel(
    const unsigned short* __restrict__ Qh, const unsigned short* __restrict__ Ql,
    const unsigned short* __restrict__ Bph, const unsigned short* __restrict__ Bpl,
    float* __restrict__ d2)
{
    __shared__ unsigned short AhS[32][40], AlS[32][40];    // +8 pad vs 32
    __shared__ unsigned short BhS[256][40], BlS[256][40];

    const int tid  = threadIdx.x;
    const int lane = tid & 63, w = tid >> 6;
    const int quad = lane >> 4, rlo = lane & 15;
    const int m0 = blockIdx.x * 32;      // sample tile (fast-varying blockIdx -> shared beta tile stays L2-hot)
    const int n0 = blockIdx.y * 256;     // cluster tile

    // staging assignments: A (Qh+Ql): 256 16B-segs; B: 2048 segs (8 iters)
    const int aplane = tid >> 7, aidx = tid & 127;
    const int arow = aidx >> 2, aseg = aidx & 3;
    const unsigned short* aSrc = (aplane ? Ql : Qh) + (size_t)(m0 + arow) * KP + aseg * 8;
    unsigned short* aDst = (aplane ? &AlS[0][0] : &AhS[0][0]) + arow * 40 + aseg * 8;

    const unsigned short* bSrc[8];
    unsigned short* bDst[8];
    #pragma unroll
    for (int it = 0; it < 8; ++it) {
        const int idx2 = it * 256 + tid;
        const int bplane = idx2 >> 10, idx = idx2 & 1023;
        const int br = idx >> 2, bseg = idx & 3;
        bSrc[it] = (bplane ? Bpl : Bph) + (size_t)(n0 + br) * KP + bseg * 8;
        bDst[it] = (bplane ? &BlS[0][0] : &BhS[0][0]) + br * 40 + bseg * 8;
    }

    ushort8 pa, pb[8];
    // prefetch kt=0
    pa = *(const ushort8*)(aSrc);
    #pragma unroll
    for (int it = 0; it < 8; ++it) pb[it] = *(const ushort8*)(bSrc[it]);

    floatx4 acc[2][4] = {};

    for (int kt = 0; kt < KT_STEPS; ++kt) {
        __syncthreads();
        *(ushort8*)aDst = pa;
        #pragma unroll
        for (int it = 0; it < 8; ++it) *(ushort8*)bDst[it] = pb[it];
        __syncthreads();

        if (kt + 1 < KT_STEPS) {
            const int ko = (kt + 1) * 32;
            pa = *(const ushort8*)(aSrc + ko);
            #pragma unroll
            for (int it = 0; it < 8; ++it) pb[it] = *(const ushort8*)(bSrc[it] + ko);
        }

        short8 ah[2], al[2], bh[4], bl[4];
        #pragma unroll
        for (int i = 0; i < 2; ++i) {
            ah[i] = *(const short8*)&AhS[i * 16 + rlo][quad * 8];
            al[i] = *(const short8*)&AlS[i * 16 + rlo][quad * 8];
        }
        #pragma unroll
        for (int j = 0; j < 4; ++j) {
            const int r = w * 64 + j * 16 + rlo;
            bh[j] = *(const short8*)&BhS[r][quad * 8];
            bl[j] = *(const short8*)&BlS[r][quad * 8];
        }
        #pragma unroll
        for (int i = 0; i < 2; ++i)
            #pragma unroll
            for (int j = 0; j < 4; ++j) {
                acc[i][j] = __builtin_amdgcn_mfma_f32_16x16x32_bf16(al[i], bh[j], acc[i][j], 0, 0, 0);
                acc[i][j] = __builtin_amdgcn_mfma_f32_16x16x32_bf16(ah[i], bl[j], acc[i][j], 0, 0, 0);
                acc[i][j] = __builtin_amdgcn_mfma_f32_16x16x32_bf16(ah[i], bh[j], acc[i][j], 0, 0, 0);
            }
    }

    // C layout (verified m89): col = lane&15, row = (lane>>4)*4 + reg
    #pragma unroll
    for (int i = 0; i < 2; ++i)
        #pragma unroll
        for (int j = 0; j < 4; ++j) {
            const int m = m0 + i * 16 + quad * 4;
            const int n = n0 + w * 64 + j * 16 + rlo;
            #pragma unroll
            for (int r = 0; r < 4; ++r)
                d2[(size_t)(m + r) * NC + n] = acc[i][j][r];
        }
}

// ---------------- scores / argmaxes: one wave per sample ----------------
__global__ __launch_bounds__(64) void score_kernel(
    const float* __restrict__ d2, const float* __restrict__ labf,
    float* __restrict__ out)
{
    const int s = blockIdx.x;
    const int l = threadIdx.x;

    float numer[NK];
    #pragma unroll
    for (int q = 0; q < NK; ++q) numer[q] = 0.f;
    float denom = 0.f, gmax = -1.f;
    int gidx = 0;

    for (int i = 0; i < NC / 64; ++i) {          // lane-strided, ascending per lane
        const int c = l + i * 64;
        const float G = __expf(-0.5f * d2[(size_t)s * NC + c]);
        denom += G;
        const int lab = (int)labf[c];
        #pragma unroll
        for (int q = 0; q < NK; ++q) numer[q] += (q == lab) ? G : 0.f;
        if (G > gmax) { gmax = G; gidx = c; }
    }

    // wave reduction (width 64); ties -> lowest cluster index (jnp first-max)
    #pragma unroll
    for (int off = 32; off > 0; off >>= 1) {
        const float og = __shfl_down(gmax, off);
        const int   oi = __shfl_down(gidx, off);
        if (og > gmax || (og == gmax && oi < gidx)) { gmax = og; gidx = oi; }
        denom += __shfl_down(denom, off);
        #pragma unroll
        for (int q = 0; q < NK; ++q) numer[q] += __shfl_down(numer[q], off);
    }

    if (l == 0) {
        const float inv = 1.0f / (denom + 1e-12f);
        float best = -1.f; int pk = 0;
        #pragma unroll
        for (int q = 0; q < NK; ++q) {
            const float sc = numer[q] * inv;
            out[(size_t)s * NK + q] = sc;
            if (sc > best) { best = sc; pk = q; }
        }
        out[(size_t)NS * NK + s]      = (float)pk;    // pred
        out[(size_t)NS * NK + NS + s] = (float)gidx;  // clusters
    }
}

extern "C" void kernel_launch(void* const* d_in, const int* in_sizes, int n_in,
                              void* d_out, int out_size, void* d_ws, size_t ws_size,
                              hipStream_t stream)
{
    const float* data = (const float*)d_in[0];
    const float* n    = (const float*)d_in[2];
    const float* mu   = (const float*)d_in[3];
    const float* S    = (const float*)d_in[4];
    const int*   clab = (const int*)d_in[5];

    // ws byte layout (Binv/bvec/kcon alias the Qh region: dead before qbuild runs)
    char* w = (char*)d_ws;
    unsigned short* Qh  = (unsigned short*)(w);                 // 17,825,792 B
    unsigned short* Ql  = (unsigned short*)(w + 17825792);      // 17,825,792 B
    unsigned short* Bph = (unsigned short*)(w + 35651584);      //  2,228,224 B
    unsigned short* Bpl = (unsigned short*)(w + 37879808);      //  2,228,224 B
    float* d2   = (float*)(w + 40108032);                       //  8,388,608 B
    float* labf = (float*)(w + 48496640);                       //      2,048 B
    int*   eop  = (int*)  (w + 48498688);                       //      8,320 B
    int*   dop  = (int*)  (w + 48507008);                       //      8,320 B  (end 48,515,328)
    float* Binv = (float*)(w);                                  // alias in Qh region
    float* bvec = (float*)(w + 8388608);
    float* kcon = (float*)(w + 8519680);

    hipLaunchKernelGGL(table_kernel, dim3(1),   dim3(64),  0, stream, eop, dop);
    hipLaunchKernelGGL(prep_kernel,  dim3(NC),  dim3(64),  0, stream,
                       S, n, mu, clab, Binv, bvec, kcon, labf);
    hipLaunchKernelGGL(pack_kernel,  dim3(NC),  dim3(256), 0, stream,
                       Binv, bvec, kcon, eop, dop, Bph, Bpl);
    hipLaunchKernelGGL(qbuild_kernel, dim3(NS), dim3(256), 0, stream,
                       data, eop, dop, Qh, Ql);
    hipLaunchKernelGGL(gemm_kernel,  dim3(NS / 32, NC / 256), dim3(256), 0, stream,
                       Qh, Ql, Bph, Bpl, d2);
    hipLaunchKernelGGL(score_kernel, dim3(NS),  dim3(64),  0, stream,
                       d2, labf, (float*)d_out);
}

// Round 5
// 228.636 us; speedup vs baseline: 3.0235x; 3.0235x over previous
//
#include <hip/hip_runtime.h>
#include <hip/hip_bf16.h>
#include <math.h>

#define NS 4096      // samples
#define NC 512       // clusters
#define ND 64        // feature dim
#define NK 10        // classes
#define NPAIR 2080   // upper-triangle pairs (e<=d) of 64x64
#define KP 2176      // 2080 + 64 (linear) + 1 (const) + 31 zero-pad; 68*32
#define BOFF 2080
#define KOFF 2144
#define KT_STEPS (KP / 32)   // 68

typedef __attribute__((ext_vector_type(8))) short short8;
typedef __attribute__((ext_vector_type(8))) unsigned short ushort8;
typedef __attribute__((ext_vector_type(4))) float floatx4;

__device__ inline unsigned short f2b(float x) {
    __hip_bfloat16 h = __float2bfloat16(x);           // RNE
    return __builtin_bit_cast(unsigned short, h);
}
__device__ inline float b2f(unsigned short u) {
    __hip_bfloat16 h = __builtin_bit_cast(__hip_bfloat16, u);
    return __bfloat162float(h);
}

// ---------------- pair-index tables ----------------
__global__ void table_kernel(int* __restrict__ eop, int* __restrict__ dop) {
    const int e = threadIdx.x;                        // 64 threads
    int off = e * 64 - (e * (e - 1)) / 2;             // row e starts here
    for (int d = e; d < 64; ++d) { eop[off + d - e] = e; dop[off + d - e] = d; }
}

// ---------------- Sigma^-1: wave-per-matrix GJ, matrix in LDS ----------------
// R3/R4 post-mortem: register-array GJ demoted A[] to scratch (dynamic index
// after unroll bail) -> 535us. Here all dynamic indexing is in LDS; one wave,
// no __syncthreads (same-wave DS ops are pipe-ordered). Lane j owns column j,
// column-major with +1 pad: every pattern used is <=2-way (free).
__global__ __launch_bounds__(64) void prep_kernel(
    const float* __restrict__ S, const float* __restrict__ n,
    const float* __restrict__ mu, const int* __restrict__ clab,
    float* __restrict__ Binv, float* __restrict__ bvec,
    float* __restrict__ kcon, float* __restrict__ labf)
{
    const int c = blockIdx.x;
    const int j = threadIdx.x;                        // column owned by this lane
    __shared__ float Acol[ND][ND + 1];                // Acol[j][i] = A[i][j]
    __shared__ float cbuf[ND];                        // snapshot of column k

    const float inv_nc = 1.0f / n[c];
    #pragma unroll
    for (int i0 = 0; i0 < ND; i0 += 4) {
        float4 v;
        v.x = S[(size_t)c * ND * ND + (i0 + 0) * ND + j] * inv_nc;
        v.y = S[(size_t)c * ND * ND + (i0 + 1) * ND + j] * inv_nc;
        v.z = S[(size_t)c * ND * ND + (i0 + 2) * ND + j] * inv_nc;
        v.w = S[(size_t)c * ND * ND + (i0 + 3) * ND + j] * inv_nc;
        if (j - i0 >= 0 && j - i0 < 4) ((float*)&v)[j - i0] += 1e-6f;  // + eps*I
        *(float4*)&Acol[j][i0] = v;
    }
    __builtin_amdgcn_wave_barrier();

    for (int k = 0; k < ND; ++k) {
        // row k: scale by 1/pivot (implicit identity at j==k)
        float rowk = Acol[j][k];
        const float p = Acol[k][k];                   // uniform read (broadcast)
        const float ip = 1.0f / p;
        rowk = (j == k ? 1.0f : rowk) * ip;
        Acol[j][k] = rowk;
        // snapshot column k (old values; only [k][k] was touched above, and we
        // zero that element anyway so the update leaves row k alone)
        float cj = Acol[k][j];
        cj = (j == k) ? 0.0f : cj;
        cbuf[j] = cj;
        __builtin_amdgcn_wave_barrier();
        const float mj = (j == k) ? 0.0f : 1.0f;      // column-k pre-zero
        #pragma unroll
        for (int i16 = 0; i16 < ND / 4; ++i16) {
            const float4 c4 = *(const float4*)&cbuf[i16 * 4];     // uniform b128
            float4 a4 = *(float4*)&Acol[j][i16 * 4];
            a4.x = a4.x * mj - c4.x * rowk;
            a4.y = a4.y * mj - c4.y * rowk;
            a4.z = a4.z * mj - c4.z * rowk;
            a4.w = a4.w * mj - c4.w * rowk;
            *(float4*)&Acol[j][i16 * 4] = a4;
        }
        if (j == k) Acol[j][k] = rowk;                // restore A[k][k] = 1/p
        __builtin_amdgcn_wave_barrier();
    }

    // store Sinv (Acol[j][i] = Sinv[i][j]) + fused bvec/kcon
    float y = 0.f;
    #pragma unroll
    for (int i0 = 0; i0 < ND; i0 += 4) {
        const float4 v = *(const float4*)&Acol[j][i0];
        Binv[(size_t)c * ND * ND + (i0 + 0) * ND + j] = v.x;
        Binv[(size_t)c * ND * ND + (i0 + 1) * ND + j] = v.y;
        Binv[(size_t)c * ND * ND + (i0 + 2) * ND + j] = v.z;
        Binv[(size_t)c * ND * ND + (i0 + 3) * ND + j] = v.w;
        y += v.x * mu[c * ND + i0] + v.y * mu[c * ND + i0 + 1]
           + v.z * mu[c * ND + i0 + 2] + v.w * mu[c * ND + i0 + 3];
    }
    bvec[c * ND + j] = -2.0f * y;                     // y = Sinv mu (symmetric)

    float kk = mu[c * ND + j] * y;                    // kcon = mu . y
    #pragma unroll
    for (int off = 32; off > 0; off >>= 1) kk += __shfl_down(kk, off);
    if (j == 0) {
        kcon[c] = kk;
        int lab = 0;
        for (int q = 0; q < NK; ++q) if (clab[c * NK + q] != 0) lab = q;
        labf[c] = (float)lab;
    }
}

// ---------------- pack beta_c = [sym-folded Binv, b, k, 0pad] as bf16 hi/lo ----------------
__global__ __launch_bounds__(256) void pack_kernel(
    const float* __restrict__ Binv, const float* __restrict__ bvec,
    const float* __restrict__ kcon, const int* __restrict__ eop,
    const int* __restrict__ dop, unsigned short* __restrict__ Bph,
    unsigned short* __restrict__ Bpl)
{
    const int c = blockIdx.x;
    const float* __restrict__ B = Binv + (size_t)c * ND * ND;
    for (int p = threadIdx.x; p < KP; p += 256) {
        float val;
        if (p < NPAIR) {
            const int e = eop[p], d = dop[p];
            val = (e == d) ? B[e * 64 + e] : (B[e * 64 + d] + B[d * 64 + e]);
        } else if (p < KOFF) val = bvec[c * ND + (p - BOFF)];
        else if (p == KOFF)  val = kcon[c];
        else                 val = 0.f;
        const unsigned short h = f2b(val);
        const unsigned short l = f2b(val - b2f(h));
        Bph[(size_t)c * KP + p] = h;
        Bpl[(size_t)c * KP + p] = l;
    }
}

// ---------------- Q rows: [z_e*z_d (e<=d), z, 1, 0pad] as bf16 hi/lo ----------------
__global__ __launch_bounds__(256) void qbuild_kernel(
    const float* __restrict__ data, const int* __restrict__ eop,
    const int* __restrict__ dop, unsigned short* __restrict__ Qh,
    unsigned short* __restrict__ Ql)
{
    const int s = blockIdx.x;
    __shared__ float z[ND];
    if (threadIdx.x < ND) z[threadIdx.x] = data[(size_t)s * ND + threadIdx.x];
    __syncthreads();
    for (int p = threadIdx.x; p < KP; p += 256) {
        float val;
        if (p < NPAIR)      val = z[eop[p]] * z[dop[p]];
        else if (p < KOFF)  val = z[p - BOFF];
        else if (p == KOFF) val = 1.0f;
        else                val = 0.f;
        const unsigned short h = f2b(val);
        const unsigned short l = f2b(val - b2f(h));
        Qh[(size_t)s * KP + p] = h;
        Ql[(size_t)s * KP + p] = l;
    }
}

// ---------------- d2[s][c] = Q · Beta^T via bf16x3 MFMA ----------------
// Block tile: 32 samples x 256 clusters, K-chunk 32, 4 waves (each 32x64).
__global__ __launch_bounds__(256) void gemm_kernel(
    const unsigned short* __restrict__ Qh, const unsigned short* __restrict__ Ql,
    const unsigned short* __restrict__ Bph, const unsigned short* __restrict__ Bpl,
    float* __restrict__ d2)
{
    __shared__ unsigned short AhS[32][40], AlS[32][40];    // +8 pad vs 32
    __shared__ unsigned short BhS[256][40], BlS[256][40];

    const int tid  = threadIdx.x;
    const int lane = tid & 63, w = tid >> 6;
    const int quad = lane >> 4, rlo = lane & 15;
    const int m0 = blockIdx.x * 32;      // sample tile (fast-varying blockIdx -> shared beta tile stays L2-hot)
    const int n0 = blockIdx.y * 256;     // cluster tile

    // staging assignments: A (Qh+Ql): 256 16B-segs; B: 2048 segs (8 iters)
    const int aplane = tid >> 7, aidx = tid & 127;
    const int arow = aidx >> 2, aseg = aidx & 3;
    const unsigned short* aSrc = (aplane ? Ql : Qh) + (size_t)(m0 + arow) * KP + aseg * 8;
    unsigned short* aDst = (aplane ? &AlS[0][0] : &AhS[0][0]) + arow * 40 + aseg * 8;

    const unsigned short* bSrc[8];
    unsigned short* bDst[8];
    #pragma unroll
    for (int it = 0; it < 8; ++it) {
        const int idx2 = it * 256 + tid;
        const int bplane = idx2 >> 10, idx = idx2 & 1023;
        const int br = idx >> 2, bseg = idx & 3;
        bSrc[it] = (bplane ? Bpl : Bph) + (size_t)(n0 + br) * KP + bseg * 8;
        bDst[it] = (bplane ? &BlS[0][0] : &BhS[0][0]) + br * 40 + bseg * 8;
    }

    ushort8 pa, pb[8];
    // prefetch kt=0
    pa = *(const ushort8*)(aSrc);
    #pragma unroll
    for (int it = 0; it < 8; ++it) pb[it] = *(const ushort8*)(bSrc[it]);

    floatx4 acc[2][4] = {};

    for (int kt = 0; kt < KT_STEPS; ++kt) {
        __syncthreads();
        *(ushort8*)aDst = pa;
        #pragma unroll
        for (int it = 0; it < 8; ++it) *(ushort8*)bDst[it] = pb[it];
        __syncthreads();

        if (kt + 1 < KT_STEPS) {
            const int ko = (kt + 1) * 32;
            pa = *(const ushort8*)(aSrc + ko);
            #pragma unroll
            for (int it = 0; it < 8; ++it) pb[it] = *(const ushort8*)(bSrc[it] + ko);
        }

        short8 ah[2], al[2], bh[4], bl[4];
        #pragma unroll
        for (int i = 0; i < 2; ++i) {
            ah[i] = *(const short8*)&AhS[i * 16 + rlo][quad * 8];
            al[i] = *(const short8*)&AlS[i * 16 + rlo][quad * 8];
        }
        #pragma unroll
        for (int j = 0; j < 4; ++j) {
            const int r = w * 64 + j * 16 + rlo;
            bh[j] = *(const short8*)&BhS[r][quad * 8];
            bl[j] = *(const short8*)&BlS[r][quad * 8];
        }
        #pragma unroll
        for (int i = 0; i < 2; ++i)
            #pragma unroll
            for (int j = 0; j < 4; ++j) {
                acc[i][j] = __builtin_amdgcn_mfma_f32_16x16x32_bf16(al[i], bh[j], acc[i][j], 0, 0, 0);
                acc[i][j] = __builtin_amdgcn_mfma_f32_16x16x32_bf16(ah[i], bl[j], acc[i][j], 0, 0, 0);
                acc[i][j] = __builtin_amdgcn_mfma_f32_16x16x32_bf16(ah[i], bh[j], acc[i][j], 0, 0, 0);
            }
    }

    // C layout (verified m89): col = lane&15, row = (lane>>4)*4 + reg
    #pragma unroll
    for (int i = 0; i < 2; ++i)
        #pragma unroll
        for (int j = 0; j < 4; ++j) {
            const int m = m0 + i * 16 + quad * 4;
            const int n = n0 + w * 64 + j * 16 + rlo;
            #pragma unroll
            for (int r = 0; r < 4; ++r)
                d2[(size_t)(m + r) * NC + n] = acc[i][j][r];
        }
}

// ---------------- scores / argmaxes: one wave per sample ----------------
__global__ __launch_bounds__(64) void score_kernel(
    const float* __restrict__ d2, const float* __restrict__ labf,
    float* __restrict__ out)
{
    const int s = blockIdx.x;
    const int l = threadIdx.x;

    float numer[NK];
    #pragma unroll
    for (int q = 0; q < NK; ++q) numer[q] = 0.f;
    float denom = 0.f, gmax = -1.f;
    int gidx = 0;

    for (int i = 0; i < NC / 64; ++i) {          // lane-strided, ascending per lane
        const int c = l + i * 64;
        const float G = __expf(-0.5f * d2[(size_t)s * NC + c]);
        denom += G;
        const int lab = (int)labf[c];
        #pragma unroll
        for (int q = 0; q < NK; ++q) numer[q] += (q == lab) ? G : 0.f;
        if (G > gmax) { gmax = G; gidx = c; }
    }

    // wave reduction (width 64); ties -> lowest cluster index (jnp first-max)
    #pragma unroll
    for (int off = 32; off > 0; off >>= 1) {
        const float og = __shfl_down(gmax, off);
        const int   oi = __shfl_down(gidx, off);
        if (og > gmax || (og == gmax && oi < gidx)) { gmax = og; gidx = oi; }
        denom += __shfl_down(denom, off);
        #pragma unroll
        for (int q = 0; q < NK; ++q) numer[q] += __shfl_down(numer[q], off);
    }

    if (l == 0) {
        const float inv = 1.0f / (denom + 1e-12f);
        float best = -1.f; int pk = 0;
        #pragma unroll
        for (int q = 0; q < NK; ++q) {
            const float sc = numer[q] * inv;
            out[(size_t)s * NK + q] = sc;
            if (sc > best) { best = sc; pk = q; }
        }
        out[(size_t)NS * NK + s]      = (float)pk;    // pred
        out[(size_t)NS * NK + NS + s] = (float)gidx;  // clusters
    }
}

extern "C" void kernel_launch(void* const* d_in, const int* in_sizes, int n_in,
                              void* d_out, int out_size, void* d_ws, size_t ws_size,
                              hipStream_t stream)
{
    const float* data = (const float*)d_in[0];
    const float* n    = (const float*)d_in[2];
    const float* mu   = (const float*)d_in[3];
    const float* S    = (const float*)d_in[4];
    const int*   clab = (const int*)d_in[5];

    // ws byte layout (Binv/bvec/kcon alias the Qh region: dead before qbuild runs)
    char* w = (char*)d_ws;
    unsigned short* Qh  = (unsigned short*)(w);                 // 17,825,792 B
    unsigned short* Ql  = (unsigned short*)(w + 17825792);      // 17,825,792 B
    unsigned short* Bph = (unsigned short*)(w + 35651584);      //  2,228,224 B
    unsigned short* Bpl = (unsigned short*)(w + 37879808);      //  2,228,224 B
    float* d2   = (float*)(w + 40108032);                       //  8,388,608 B
    float* labf = (float*)(w + 48496640);                       //      2,048 B
    int*   eop  = (int*)  (w + 48498688);                       //      8,320 B
    int*   dop  = (int*)  (w + 48507008);                       //      8,320 B  (end 48,515,328)
    float* Binv = (float*)(w);                                  // alias in Qh region
    float* bvec = (float*)(w + 8388608);
    float* kcon = (float*)(w + 8519680);

    hipLaunchKernelGGL(table_kernel, dim3(1),   dim3(64),  0, stream, eop, dop);
    hipLaunchKernelGGL(prep_kernel,  dim3(NC),  dim3(64),  0, stream,
                       S, n, mu, clab, Binv, bvec, kcon, labf);
    hipLaunchKernelGGL(pack_kernel,  dim3(NC),  dim3(256), 0, stream,
                       Binv, bvec, kcon, eop, dop, Bph, Bpl);
    hipLaunchKernelGGL(qbuild_kernel, dim3(NS), dim3(256), 0, stream,
                       data, eop, dop, Qh, Ql);
    hipLaunchKernelGGL(gemm_kernel,  dim3(NS / 32, NC / 256), dim3(256), 0, stream,
                       Qh, Ql, Bph, Bpl, d2);
    hipLaunchKernelGGL(score_kernel, dim3(NS),  dim3(64),  0, stream,
                       d2, labf, (float*)d_out);
}

// Round 6
// 218.468 us; speedup vs baseline: 3.1642x; 1.0465x over previous
//
#include <hip/hip_runtime.h>
#include <hip/hip_bf16.h>
#include <math.h>

#define NS 4096      // samples
#define NC 512       // clusters
#define ND 64        // feature dim
#define NK 10        // classes
#define NPAIR 2080   // upper-triangle pairs (e<=d) of 64x64
#define KP 2176      // 2080 + 64 (linear) + 1 (const) + 31 zero-pad; 68*32
#define BOFF 2080
#define KOFF 2144
#define KSPLIT 4
#define KT_PER (KP / 32 / KSPLIT)   // 17 k-chunks per split block

typedef __attribute__((ext_vector_type(8))) short short8;
typedef __attribute__((ext_vector_type(8))) unsigned short ushort8;
typedef __attribute__((ext_vector_type(4))) float floatx4;

__device__ inline unsigned short f2b(float x) {
    __hip_bfloat16 h = __float2bfloat16(x);           // RNE
    return __builtin_bit_cast(unsigned short, h);
}
__device__ inline float b2f(unsigned short u) {
    __hip_bfloat16 h = __builtin_bit_cast(__hip_bfloat16, u);
    return __bfloat162float(h);
}

// ---------------- pair-index tables ----------------
__global__ void table_kernel(int* __restrict__ eop, int* __restrict__ dop) {
    const int e = threadIdx.x;                        // 64 threads
    int off = e * 64 - (e * (e - 1)) / 2;             // row e starts here
    for (int d = e; d < 64; ++d) { eop[off + d - e] = e; dop[off + d - e] = d; }
}

// ---------------- Sigma^-1 (LDS GJ) + fused beta-pack ----------------
// Wave-per-cluster GJ in LDS (R5-verified). Then pack beta directly from LDS:
// kills pack_kernel and the 16 MB Binv global round-trip.
__global__ __launch_bounds__(64) void prep_kernel(
    const float* __restrict__ S, const float* __restrict__ n,
    const float* __restrict__ mu, const int* __restrict__ clab,
    const int* __restrict__ eop, const int* __restrict__ dop,
    unsigned short* __restrict__ Bph, unsigned short* __restrict__ Bpl,
    float* __restrict__ labf)
{
    const int c = blockIdx.x;
    const int j = threadIdx.x;                        // column owned by this lane
    __shared__ float Acol[ND][ND + 1];                // Acol[j][i] = A[i][j]
    __shared__ float cbuf[ND];                        // col-k snapshot / bvec

    const float inv_nc = 1.0f / n[c];
    #pragma unroll
    for (int i0 = 0; i0 < ND; i0 += 4) {
        float4 v;
        v.x = S[(size_t)c * ND * ND + (i0 + 0) * ND + j] * inv_nc;
        v.y = S[(size_t)c * ND * ND + (i0 + 1) * ND + j] * inv_nc;
        v.z = S[(size_t)c * ND * ND + (i0 + 2) * ND + j] * inv_nc;
        v.w = S[(size_t)c * ND * ND + (i0 + 3) * ND + j] * inv_nc;
        if (j - i0 >= 0 && j - i0 < 4) ((float*)&v)[j - i0] += 1e-6f;  // + eps*I
        *(float4*)&Acol[j][i0] = v;
    }
    __builtin_amdgcn_wave_barrier();

    for (int k = 0; k < ND; ++k) {
        float rowk = Acol[j][k];
        const float p = Acol[k][k];                   // uniform read (broadcast)
        const float ip = 1.0f / p;
        rowk = (j == k ? 1.0f : rowk) * ip;
        Acol[j][k] = rowk;
        float cj = Acol[k][j];
        cj = (j == k) ? 0.0f : cj;
        cbuf[j] = cj;
        __builtin_amdgcn_wave_barrier();
        const float mj = (j == k) ? 0.0f : 1.0f;      // column-k pre-zero
        #pragma unroll
        for (int i16 = 0; i16 < ND / 4; ++i16) {
            const float4 c4 = *(const float4*)&cbuf[i16 * 4];     // uniform b128
            float4 a4 = *(float4*)&Acol[j][i16 * 4];
            a4.x = a4.x * mj - c4.x * rowk;
            a4.y = a4.y * mj - c4.y * rowk;
            a4.z = a4.z * mj - c4.z * rowk;
            a4.w = a4.w * mj - c4.w * rowk;
            *(float4*)&Acol[j][i16 * 4] = a4;
        }
        if (j == k) Acol[j][k] = rowk;                // restore A[k][k] = 1/p
        __builtin_amdgcn_wave_barrier();
    }

    // y = Sinv mu (symmetric: column dot works), bvec -> LDS, kcon -> shuffle
    float y = 0.f;
    #pragma unroll
    for (int i = 0; i < ND; ++i) y += Acol[j][i] * mu[c * ND + i];
    __builtin_amdgcn_wave_barrier();                  // GJ reads of cbuf done
    cbuf[j] = -2.0f * y;                              // bvec values
    float kk = mu[c * ND + j] * y;
    #pragma unroll
    for (int off = 32; off > 0; off >>= 1) kk += __shfl_down(kk, off);
    const float kks = __shfl(kk, 0);
    if (j == 0) {
        int lab = 0;
        for (int q = 0; q < NK; ++q) if (clab[c * NK + q] != 0) lab = q;
        labf[c] = (float)lab;
    }
    __builtin_amdgcn_wave_barrier();

    // fused pack: beta = [sym-folded Sinv, b, k, 0pad] as bf16 hi/lo
    unsigned short* __restrict__ ph = Bph + (size_t)c * KP;
    unsigned short* __restrict__ pl = Bpl + (size_t)c * KP;
    #pragma unroll
    for (int t = 0; t < KP / 64; ++t) {               // 34 iters, p = t*64+j
        const int p = t * 64 + j;
        float val;
        if (p < NPAIR) {
            const int e = eop[p], d = dop[p];
            val = (e == d) ? Acol[e][e] : (Acol[d][e] + Acol[e][d]);
        } else if (p < KOFF) val = cbuf[p - BOFF];
        else if (p == KOFF)  val = kks;
        else                 val = 0.f;
        const unsigned short h = f2b(val);
        const unsigned short l = f2b(val - b2f(h));
        ph[p] = h;
        pl[p] = l;
    }
}

// ---------------- Q rows: [z_e*z_d (e<=d), z, 1, 0pad] as bf16 hi/lo ----------------
// Also zeroes this sample's d2 row (split-K gemm accumulates with atomics).
__global__ __launch_bounds__(256) void qbuild_kernel(
    const float* __restrict__ data, const int* __restrict__ eop,
    const int* __restrict__ dop, unsigned short* __restrict__ Qh,
    unsigned short* __restrict__ Ql, float* __restrict__ d2)
{
    const int s = blockIdx.x;
    __shared__ float z[ND];
    if (threadIdx.x < ND) z[threadIdx.x] = data[(size_t)s * ND + threadIdx.x];
    *(float2*)&d2[(size_t)s * NC + threadIdx.x * 2] = make_float2(0.f, 0.f);
    __syncthreads();
    for (int p = threadIdx.x; p < KP; p += 256) {
        float val;
        if (p < NPAIR)      val = z[eop[p]] * z[dop[p]];
        else if (p < KOFF)  val = z[p - BOFF];
        else if (p == KOFF) val = 1.0f;
        else                val = 0.f;
        const unsigned short h = f2b(val);
        const unsigned short l = f2b(val - b2f(h));
        Qh[(size_t)s * KP + p] = h;
        Ql[(size_t)s * KP + p] = l;
    }
}

// ---------------- d2[s][c] = Q · Beta^T via bf16x3 MFMA, split-K x4 ----------------
// Tile 32x256, 4 waves; blockIdx.z = K-slice (17 of 68 k-chunks); atomicAdd epilogue.
// R5: 1 block/CU -> 10% occupancy, barrier-bound. Split-K gives 3 resident blocks/CU.
__global__ __launch_bounds__(256) void gemm_kernel(
    const unsigned short* __restrict__ Qh, const unsigned short* __restrict__ Ql,
    const unsigned short* __restrict__ Bph, const unsigned short* __restrict__ Bpl,
    float* __restrict__ d2)
{
    __shared__ unsigned short AhS[32][40], AlS[32][40];    // +8 pad vs 32
    __shared__ unsigned short BhS[256][40], BlS[256][40];

    const int tid  = threadIdx.x;
    const int lane = tid & 63, w = tid >> 6;
    const int quad = lane >> 4, rlo = lane & 15;
    const int m0 = blockIdx.x * 32;      // sample tile
    const int n0 = blockIdx.y * 256;     // cluster tile
    const int koff0 = blockIdx.z * KT_PER * 32;   // this block's K-slice start

    const int aplane = tid >> 7, aidx = tid & 127;
    const int arow = aidx >> 2, aseg = aidx & 3;
    const unsigned short* aSrc = (aplane ? Ql : Qh) + (size_t)(m0 + arow) * KP + aseg * 8 + koff0;
    unsigned short* aDst = (aplane ? &AlS[0][0] : &AhS[0][0]) + arow * 40 + aseg * 8;

    const unsigned short* bSrc[8];
    unsigned short* bDst[8];
    #pragma unroll
    for (int it = 0; it < 8; ++it) {
        const int idx2 = it * 256 + tid;
        const int bplane = idx2 >> 10, idx = idx2 & 1023;
        const int br = idx >> 2, bseg = idx & 3;
        bSrc[it] = (bplane ? Bpl : Bph) + (size_t)(n0 + br) * KP + bseg * 8 + koff0;
        bDst[it] = (bplane ? &BlS[0][0] : &BhS[0][0]) + br * 40 + bseg * 8;
    }

    ushort8 pa, pb[8];
    pa = *(const ushort8*)(aSrc);
    #pragma unroll
    for (int it = 0; it < 8; ++it) pb[it] = *(const ushort8*)(bSrc[it]);

    floatx4 acc[2][4] = {};

    for (int kt = 0; kt < KT_PER; ++kt) {
        __syncthreads();
        *(ushort8*)aDst = pa;
        #pragma unroll
        for (int it = 0; it < 8; ++it) *(ushort8*)bDst[it] = pb[it];
        __syncthreads();

        if (kt + 1 < KT_PER) {
            const int ko = (kt + 1) * 32;
            pa = *(const ushort8*)(aSrc + ko);
            #pragma unroll
            for (int it = 0; it < 8; ++it) pb[it] = *(const ushort8*)(bSrc[it] + ko);
        }

        short8 ah[2], al[2], bh[4], bl[4];
        #pragma unroll
        for (int i = 0; i < 2; ++i) {
            ah[i] = *(const short8*)&AhS[i * 16 + rlo][quad * 8];
            al[i] = *(const short8*)&AlS[i * 16 + rlo][quad * 8];
        }
        #pragma unroll
        for (int j = 0; j < 4; ++j) {
            const int r = w * 64 + j * 16 + rlo;
            bh[j] = *(const short8*)&BhS[r][quad * 8];
            bl[j] = *(const short8*)&BlS[r][quad * 8];
        }
        #pragma unroll
        for (int i = 0; i < 2; ++i)
            #pragma unroll
            for (int j = 0; j < 4; ++j) {
                acc[i][j] = __builtin_amdgcn_mfma_f32_16x16x32_bf16(al[i], bh[j], acc[i][j], 0, 0, 0);
                acc[i][j] = __builtin_amdgcn_mfma_f32_16x16x32_bf16(ah[i], bl[j], acc[i][j], 0, 0, 0);
                acc[i][j] = __builtin_amdgcn_mfma_f32_16x16x32_bf16(ah[i], bh[j], acc[i][j], 0, 0, 0);
            }
    }

    // C layout (verified m89): col = lane&15, row = (lane>>4)*4 + reg
    #pragma unroll
    for (int i = 0; i < 2; ++i)
        #pragma unroll
        for (int j = 0; j < 4; ++j) {
            const int m = m0 + i * 16 + quad * 4;
            const int n = n0 + w * 64 + j * 16 + rlo;
            #pragma unroll
            for (int r = 0; r < 4; ++r)
                atomicAdd(&d2[(size_t)(m + r) * NC + n], acc[i][j][r]);
        }
}

// ---------------- scores / argmaxes: one wave per sample ----------------
__global__ __launch_bounds__(64) void score_kernel(
    const float* __restrict__ d2, const float* __restrict__ labf,
    float* __restrict__ out)
{
    const int s = blockIdx.x;
    const int l = threadIdx.x;

    float numer[NK];
    #pragma unroll
    for (int q = 0; q < NK; ++q) numer[q] = 0.f;
    float denom = 0.f, gmax = -1.f;
    int gidx = 0;

    #pragma unroll
    for (int i = 0; i < NC / 256; ++i) {         // float4 per lane, index-ascending
        const int c0 = i * 256 + l * 4;
        const float4 v = *(const float4*)&d2[(size_t)s * NC + c0];
        #pragma unroll
        for (int r = 0; r < 4; ++r) {
            const int c = c0 + r;
            const float G = __expf(-0.5f * ((const float*)&v)[r]);
            denom += G;
            const int lab = (int)labf[c];
            #pragma unroll
            for (int q = 0; q < NK; ++q) numer[q] += (q == lab) ? G : 0.f;
            if (G > gmax) { gmax = G; gidx = c; }   // strict > keeps first index
        }
    }

    // wave reduction (width 64); ties -> lowest cluster index (jnp first-max)
    #pragma unroll
    for (int off = 32; off > 0; off >>= 1) {
        const float og = __shfl_down(gmax, off);
        const int   oi = __shfl_down(gidx, off);
        if (og > gmax || (og == gmax && oi < gidx)) { gmax = og; gidx = oi; }
        denom += __shfl_down(denom, off);
        #pragma unroll
        for (int q = 0; q < NK; ++q) numer[q] += __shfl_down(numer[q], off);
    }

    if (l == 0) {
        const float inv = 1.0f / (denom + 1e-12f);
        float best = -1.f; int pk = 0;
        #pragma unroll
        for (int q = 0; q < NK; ++q) {
            const float sc = numer[q] * inv;
            out[(size_t)s * NK + q] = sc;
            if (sc > best) { best = sc; pk = q; }
        }
        out[(size_t)NS * NK + s]      = (float)pk;    // pred
        out[(size_t)NS * NK + NS + s] = (float)gidx;  // clusters
    }
}

extern "C" void kernel_launch(void* const* d_in, const int* in_sizes, int n_in,
                              void* d_out, int out_size, void* d_ws, size_t ws_size,
                              hipStream_t stream)
{
    const float* data = (const float*)d_in[0];
    const float* n    = (const float*)d_in[2];
    const float* mu   = (const float*)d_in[3];
    const float* S    = (const float*)d_in[4];
    const int*   clab = (const int*)d_in[5];

    char* w = (char*)d_ws;
    unsigned short* Qh  = (unsigned short*)(w);                 // 17,825,792 B
    unsigned short* Ql  = (unsigned short*)(w + 17825792);      // 17,825,792 B
    unsigned short* Bph = (unsigned short*)(w + 35651584);      //  2,228,224 B
    unsigned short* Bpl = (unsigned short*)(w + 37879808);      //  2,228,224 B
    float* d2   = (float*)(w + 40108032);                       //  8,388,608 B
    float* labf = (float*)(w + 48496640);                       //      2,048 B
    int*   eop  = (int*)  (w + 48498688);                       //      8,320 B
    int*   dop  = (int*)  (w + 48507008);                       //      8,320 B  (end 48,515,328)

    hipLaunchKernelGGL(table_kernel, dim3(1),   dim3(64),  0, stream, eop, dop);
    hipLaunchKernelGGL(prep_kernel,  dim3(NC),  dim3(64),  0, stream,
                       S, n, mu, clab, eop, dop, Bph, Bpl, labf);
    hipLaunchKernelGGL(qbuild_kernel, dim3(NS), dim3(256), 0, stream,
                       data, eop, dop, Qh, Ql, d2);
    hipLaunchKernelGGL(gemm_kernel,  dim3(NS / 32, NC / 256, KSPLIT), dim3(256), 0, stream,
                       Qh, Ql, Bph, Bpl, d2);
    hipLaunchKernelGGL(score_kernel, dim3(NS),  dim3(64),  0, stream,
                       d2, labf, (float*)d_out);
}

// Round 7
// 211.986 us; speedup vs baseline: 3.2610x; 1.0306x over previous
//
#include <hip/hip_runtime.h>
#include <hip/hip_bf16.h>
#include <math.h>

#define NS 4096      // samples
#define NC 512       // clusters
#define ND 64        // feature dim
#define NK 10        // classes
#define NPAIR 2080   // upper-triangle pairs (e<=d) of 64x64
#define KP 2176      // 2080 + 64 (linear) + 1 (const) + 31 zero-pad; 68*32
#define BOFF 2080
#define KOFF 2144
#define KSPLIT 4
#define KT_PER (KP / 32 / KSPLIT)   // 17 k-chunks per split block

typedef __attribute__((ext_vector_type(8))) short short8;
typedef __attribute__((ext_vector_type(8))) unsigned short ushort8;
typedef __attribute__((ext_vector_type(4))) float floatx4;

__device__ inline unsigned short f2b(float x) {
    __hip_bfloat16 h = __float2bfloat16(x);           // RNE
    return __builtin_bit_cast(unsigned short, h);
}
__device__ inline float b2f(unsigned short u) {
    __hip_bfloat16 h = __builtin_bit_cast(__hip_bfloat16, u);
    return __bfloat162float(h);
}

// ---------------- pair-index tables ----------------
__global__ void table_kernel(int* __restrict__ eop, int* __restrict__ dop) {
    const int e = threadIdx.x;                        // 64 threads
    int off = e * 64 - (e * (e - 1)) / 2;             // row e starts here
    for (int d = e; d < 64; ++d) { eop[off + d - e] = e; dop[off + d - e] = d; }
}

// ---------------- Sigma^-1: register-resident wave GJ + fused beta-pack ------
// Lane j holds column j of A in 64 VGPRs (all indices static -> no scratch).
// Per k-step, lane k publishes its column to LDS (colk); every lane gets its
// row-k element via the symmetric-sign identity  A[k][j] = (j<k ? -1 : +1) *
// A[j][k] = +-colk[j]  (FP-exact for symmetric input: mirrored updates
// multiply identical value pairs). This removes ALL dynamic register
// indexing (R3's scratch demotion) and cuts LDS traffic ~40% vs R6 (84us,
// latency-bound at VALUBusy 5.5%).
__global__ __launch_bounds__(64, 1) void prep_kernel(
    const float* __restrict__ S, const float* __restrict__ n,
    const float* __restrict__ mu, const int* __restrict__ clab,
    const int* __restrict__ eop, const int* __restrict__ dop,
    unsigned short* __restrict__ Bph, unsigned short* __restrict__ Bpl,
    float* __restrict__ labf)
{
    const int c = blockIdx.x;
    const int j = threadIdx.x;                        // column owned by this lane
    __shared__ float colk[ND];                        // column-k broadcast
    __shared__ float Acol[ND][ND + 1];                // Sinv mirror for pack
    __shared__ float cbuf[ND];                        // bvec staging

    const float inv_nc = 1.0f / n[c];
    float A[ND];                                      // A[i] = Sigma[i][j]
    #pragma unroll
    for (int i = 0; i < ND; ++i) {
        float v = S[(size_t)c * ND * ND + i * ND + j] * inv_nc;
        if (i == j) v += 1e-6f;                       // + eps*I
        A[i] = v;
    }

    for (int k = 0; k < ND; ++k) {
        if (j == k) {                                 // publish column k (pre-update)
            #pragma unroll
            for (int i0 = 0; i0 < ND; i0 += 4)
                *(float4*)&colk[i0] = make_float4(A[i0], A[i0+1], A[i0+2], A[i0+3]);
        }
        __builtin_amdgcn_wave_barrier();
        float rp = colk[j];                           // A[j][k]
        const float pvt = colk[k];                    // pivot (uniform read)
        const float ip = 1.0f / pvt;
        rp = (j < k) ? -rp : rp;                      // A[k][j] via sign identity
        const float rowk = (j == k ? 1.0f : rp) * ip; // scaled row-k element
        const float am = (j == k) ? 0.0f : 1.0f;      // column-k pre-zero
        #pragma unroll
        for (int i0 = 0; i0 < ND; i0 += 4) {
            const float4 c4 = *(const float4*)&colk[i0];   // uniform b128
            #pragma unroll
            for (int r = 0; r < 4; ++r) {
                const int i = i0 + r;
                const float res = A[i] * am - ((const float*)&c4)[r] * rowk;
                A[i] = (i == k) ? rowk : res;         // row k gets scaled value
            }
        }
        __builtin_amdgcn_wave_barrier();
    }

    // mirror Sinv into LDS for the pack gather; fuse y = Sinv*mu
    float y = 0.f;
    #pragma unroll
    for (int i0 = 0; i0 < ND; i0 += 4) {
        *(float4*)&Acol[j][i0] = make_float4(A[i0], A[i0+1], A[i0+2], A[i0+3]);
        y += A[i0]     * mu[c * ND + i0]     + A[i0 + 1] * mu[c * ND + i0 + 1]
           + A[i0 + 2] * mu[c * ND + i0 + 2] + A[i0 + 3] * mu[c * ND + i0 + 3];
    }
    cbuf[j] = -2.0f * y;                              // bvec values
    float kk = mu[c * ND + j] * y;
    #pragma unroll
    for (int off = 32; off > 0; off >>= 1) kk += __shfl_down(kk, off);
    const float kks = __shfl(kk, 0);
    if (j == 0) {
        int lab = 0;
        for (int q = 0; q < NK; ++q) if (clab[c * NK + q] != 0) lab = q;
        labf[c] = (float)lab;
    }
    __builtin_amdgcn_wave_barrier();

    // fused pack: beta = [sym-folded Sinv, b, k, 0pad] as bf16 hi/lo
    unsigned short* __restrict__ ph = Bph + (size_t)c * KP;
    unsigned short* __restrict__ pl = Bpl + (size_t)c * KP;
    #pragma unroll
    for (int t = 0; t < KP / 64; ++t) {               // 34 iters, p = t*64+j
        const int p = t * 64 + j;
        float val;
        if (p < NPAIR) {
            const int e = eop[p], d = dop[p];
            val = (e == d) ? Acol[e][e] : (Acol[d][e] + Acol[e][d]);
        } else if (p < KOFF) val = cbuf[p - BOFF];
        else if (p == KOFF)  val = kks;
        else                 val = 0.f;
        const unsigned short h = f2b(val);
        const unsigned short l = f2b(val - b2f(h));
        ph[p] = h;
        pl[p] = l;
    }
}

// ---------------- Q rows: [z_e*z_d (e<=d), z, 1, 0pad] as bf16 hi/lo ----------------
// Also zeroes this sample's d2 row (split-K gemm accumulates with atomics).
__global__ __launch_bounds__(256) void qbuild_kernel(
    const float* __restrict__ data, const int* __restrict__ eop,
    const int* __restrict__ dop, unsigned short* __restrict__ Qh,
    unsigned short* __restrict__ Ql, float* __restrict__ d2)
{
    const int s = blockIdx.x;
    __shared__ float z[ND];
    if (threadIdx.x < ND) z[threadIdx.x] = data[(size_t)s * ND + threadIdx.x];
    *(float2*)&d2[(size_t)s * NC + threadIdx.x * 2] = make_float2(0.f, 0.f);
    __syncthreads();
    for (int p = threadIdx.x; p < KP; p += 256) {
        float val;
        if (p < NPAIR)      val = z[eop[p]] * z[dop[p]];
        else if (p < KOFF)  val = z[p - BOFF];
        else if (p == KOFF) val = 1.0f;
        else                val = 0.f;
        const unsigned short h = f2b(val);
        const unsigned short l = f2b(val - b2f(h));
        Qh[(size_t)s * KP + p] = h;
        Ql[(size_t)s * KP + p] = l;
    }
}

// ---------------- d2[s][c] = Q · Beta^T via bf16x3 MFMA, split-K x4 ----------------
// Tile 32x256, 4 waves; blockIdx.z = K-slice (17 of 68 k-chunks); atomicAdd epilogue.
__global__ __launch_bounds__(256) void gemm_kernel(
    const unsigned short* __restrict__ Qh, const unsigned short* __restrict__ Ql,
    const unsigned short* __restrict__ Bph, const unsigned short* __restrict__ Bpl,
    float* __restrict__ d2)
{
    __shared__ unsigned short AhS[32][40], AlS[32][40];    // +8 pad vs 32
    __shared__ unsigned short BhS[256][40], BlS[256][40];

    const int tid  = threadIdx.x;
    const int lane = tid & 63, w = tid >> 6;
    const int quad = lane >> 4, rlo = lane & 15;
    const int m0 = blockIdx.x * 32;      // sample tile
    const int n0 = blockIdx.y * 256;     // cluster tile
    const int koff0 = blockIdx.z * KT_PER * 32;   // this block's K-slice start

    const int aplane = tid >> 7, aidx = tid & 127;
    const int arow = aidx >> 2, aseg = aidx & 3;
    const unsigned short* aSrc = (aplane ? Ql : Qh) + (size_t)(m0 + arow) * KP + aseg * 8 + koff0;
    unsigned short* aDst = (aplane ? &AlS[0][0] : &AhS[0][0]) + arow * 40 + aseg * 8;

    const unsigned short* bSrc[8];
    unsigned short* bDst[8];
    #pragma unroll
    for (int it = 0; it < 8; ++it) {
        const int idx2 = it * 256 + tid;
        const int bplane = idx2 >> 10, idx = idx2 & 1023;
        const int br = idx >> 2, bseg = idx & 3;
        bSrc[it] = (bplane ? Bpl : Bph) + (size_t)(n0 + br) * KP + bseg * 8 + koff0;
        bDst[it] = (bplane ? &BlS[0][0] : &BhS[0][0]) + br * 40 + bseg * 8;
    }

    ushort8 pa, pb[8];
    pa = *(const ushort8*)(aSrc);
    #pragma unroll
    for (int it = 0; it < 8; ++it) pb[it] = *(const ushort8*)(bSrc[it]);

    floatx4 acc[2][4] = {};

    for (int kt = 0; kt < KT_PER; ++kt) {
        __syncthreads();
        *(ushort8*)aDst = pa;
        #pragma unroll
        for (int it = 0; it < 8; ++it) *(ushort8*)bDst[it] = pb[it];
        __syncthreads();

        if (kt + 1 < KT_PER) {
            const int ko = (kt + 1) * 32;
            pa = *(const ushort8*)(aSrc + ko);
            #pragma unroll
            for (int it = 0; it < 8; ++it) pb[it] = *(const ushort8*)(bSrc[it] + ko);
        }

        short8 ah[2], al[2], bh[4], bl[4];
        #pragma unroll
        for (int i = 0; i < 2; ++i) {
            ah[i] = *(const short8*)&AhS[i * 16 + rlo][quad * 8];
            al[i] = *(const short8*)&AlS[i * 16 + rlo][quad * 8];
        }
        #pragma unroll
        for (int j = 0; j < 4; ++j) {
            const int r = w * 64 + j * 16 + rlo;
            bh[j] = *(const short8*)&BhS[r][quad * 8];
            bl[j] = *(const short8*)&BlS[r][quad * 8];
        }
        #pragma unroll
        for (int i = 0; i < 2; ++i)
            #pragma unroll
            for (int j = 0; j < 4; ++j) {
                acc[i][j] = __builtin_amdgcn_mfma_f32_16x16x32_bf16(al[i], bh[j], acc[i][j], 0, 0, 0);
                acc[i][j] = __builtin_amdgcn_mfma_f32_16x16x32_bf16(ah[i], bl[j], acc[i][j], 0, 0, 0);
                acc[i][j] = __builtin_amdgcn_mfma_f32_16x16x32_bf16(ah[i], bh[j], acc[i][j], 0, 0, 0);
            }
    }

    // C layout (verified m89): col = lane&15, row = (lane>>4)*4 + reg
    #pragma unroll
    for (int i = 0; i < 2; ++i)
        #pragma unroll
        for (int j = 0; j < 4; ++j) {
            const int m = m0 + i * 16 + quad * 4;
            const int n = n0 + w * 64 + j * 16 + rlo;
            #pragma unroll
            for (int r = 0; r < 4; ++r)
                atomicAdd(&d2[(size_t)(m + r) * NC + n], acc[i][j][r]);
        }
}

// ---------------- scores / argmaxes: one wave per sample ----------------
__global__ __launch_bounds__(64) void score_kernel(
    const float* __restrict__ d2, const float* __restrict__ labf,
    float* __restrict__ out)
{
    const int s = blockIdx.x;
    const int l = threadIdx.x;

    float numer[NK];
    #pragma unroll
    for (int q = 0; q < NK; ++q) numer[q] = 0.f;
    float denom = 0.f, gmax = -1.f;
    int gidx = 0;

    #pragma unroll
    for (int i = 0; i < NC / 256; ++i) {         // float4 per lane, index-ascending
        const int c0 = i * 256 + l * 4;
        const float4 v = *(const float4*)&d2[(size_t)s * NC + c0];
        #pragma unroll
        for (int r = 0; r < 4; ++r) {
            const int c = c0 + r;
            const float G = __expf(-0.5f * ((const float*)&v)[r]);
            denom += G;
            const int lab = (int)labf[c];
            #pragma unroll
            for (int q = 0; q < NK; ++q) numer[q] += (q == lab) ? G : 0.f;
            if (G > gmax) { gmax = G; gidx = c; }   // strict > keeps first index
        }
    }

    // wave reduction (width 64); ties -> lowest cluster index (jnp first-max)
    #pragma unroll
    for (int off = 32; off > 0; off >>= 1) {
        const float og = __shfl_down(gmax, off);
        const int   oi = __shfl_down(gidx, off);
        if (og > gmax || (og == gmax && oi < gidx)) { gmax = og; gidx = oi; }
        denom += __shfl_down(denom, off);
        #pragma unroll
        for (int q = 0; q < NK; ++q) numer[q] += __shfl_down(numer[q], off);
    }

    if (l == 0) {
        const float inv = 1.0f / (denom + 1e-12f);
        float best = -1.f; int pk = 0;
        #pragma unroll
        for (int q = 0; q < NK; ++q) {
            const float sc = numer[q] * inv;
            out[(size_t)s * NK + q] = sc;
            if (sc > best) { best = sc; pk = q; }
        }
        out[(size_t)NS * NK + s]      = (float)pk;    // pred
        out[(size_t)NS * NK + NS + s] = (float)gidx;  // clusters
    }
}

extern "C" void kernel_launch(void* const* d_in, const int* in_sizes, int n_in,
                              void* d_out, int out_size, void* d_ws, size_t ws_size,
                              hipStream_t stream)
{
    const float* data = (const float*)d_in[0];
    const float* n    = (const float*)d_in[2];
    const float* mu   = (const float*)d_in[3];
    const float* S    = (const float*)d_in[4];
    const int*   clab = (const int*)d_in[5];

    char* w = (char*)d_ws;
    unsigned short* Qh  = (unsigned short*)(w);                 // 17,825,792 B
    unsigned short* Ql  = (unsigned short*)(w + 17825792);      // 17,825,792 B
    unsigned short* Bph = (unsigned short*)(w + 35651584);      //  2,228,224 B
    unsigned short* Bpl = (unsigned short*)(w + 37879808);      //  2,228,224 B
    float* d2   = (float*)(w + 40108032);                       //  8,388,608 B
    float* labf = (float*)(w + 48496640);                       //      2,048 B
    int*   eop  = (int*)  (w + 48498688);                       //      8,320 B
    int*   dop  = (int*)  (w + 48507008);                       //      8,320 B  (end 48,515,328)

    hipLaunchKernelGGL(table_kernel, dim3(1),   dim3(64),  0, stream, eop, dop);
    hipLaunchKernelGGL(prep_kernel,  dim3(NC),  dim3(64),  0, stream,
                       S, n, mu, clab, eop, dop, Bph, Bpl, labf);
    hipLaunchKernelGGL(qbuild_kernel, dim3(NS), dim3(256), 0, stream,
                       data, eop, dop, Qh, Ql, d2);
    hipLaunchKernelGGL(gemm_kernel,  dim3(NS / 32, NC / 256, KSPLIT), dim3(256), 0, stream,
                       Qh, Ql, Bph, Bpl, d2);
    hipLaunchKernelGGL(score_kernel, dim3(NS),  dim3(64),  0, stream,
                       d2, labf, (float*)d_out);
}